// Round 11
// baseline (170.107 us; speedup 1.0000x reference)
//
#include <hip/hip_runtime.h>
#include <cstdint>

#define NNODES 50000
#define NEDGES 800000
#define NEG 0.2f
#define NBKT 196        // buckets of 256 nodes: 196*256 = 50176 >= 50000
#define BCAP 5120       // per-bucket capacity (mean 4096, sd 64 -> 16 sigma headroom)

typedef __attribute__((ext_vector_type(8))) short short8;   // 8 bf16 (4 VGPRs)
typedef __attribute__((ext_vector_type(4))) float f32x4;

#define AS_STRIDE 136   // ushorts; 272B rows -> 16B aligned
#define CS_STRIDE 132   // floats; breaks 128-mod-32 bank aliasing

__device__ __forceinline__ float leaky(float v) { return v > 0.f ? v : NEG * v; }

__device__ __forceinline__ unsigned short f2bf(float f) {   // round-to-nearest-even
    unsigned int u = __float_as_uint(f);
    u += 0x7fff + ((u >> 16) & 1);
    return (unsigned short)(u >> 16);
}

// 256-thread block exclusive scan (shfl within wave + LDS across 4 waves)
__device__ __forceinline__ int block_excl_scan(int v, int t) {
    __shared__ int wsum[4];
    const int lane = t & 63, wv = t >> 6;
    int x = v;
    #pragma unroll
    for (int m = 1; m < 64; m <<= 1) {
        int u = __shfl_up(x, m);
        if (lane >= m) x += u;
    }
    if (lane == 63) wsum[wv] = x;
    __syncthreads();
    if (t == 0) {
        int run = 0;
        #pragma unroll
        for (int i = 0; i < 4; ++i) { int tmp = wsum[i]; wsum[i] = run; run += tmp; }
    }
    __syncthreads();
    return x - v + wsum[wv];
}

// K1: h = x @ W via bf16 MFMA. Block: 64 rows x 128 cols, K=128 one pass.
__global__ __launch_bounds__(256) void gemm_k(const float* __restrict__ x,
                                              const float* __restrict__ W,
                                              unsigned short* __restrict__ hb,
                                              const float* __restrict__ att_src,
                                              const float* __restrict__ att_dst,
                                              float* __restrict__ a_src,
                                              float* __restrict__ a_dst) {
    __shared__ __align__(16) char smem[52224];
    unsigned short* As = (unsigned short*)smem;            // [64][AS_STRIDE] bf16
    unsigned short* Bs = (unsigned short*)(smem + 17408);  // WT [128][AS_STRIDE] bf16
    float*          Cs = (float*)smem;                     // [64][CS_STRIDE] fp32 (aliases)

    const int tid = threadIdx.x;
    const int rbase = blockIdx.x * 64;

    // stage A: x[rbase..rbase+63][0..127] fp32 -> bf16 LDS
    #pragma unroll
    for (int i = 0; i < 8; ++i) {
        int f = tid + i * 256;           // float4 index; 32 per row
        int r = f >> 5, c4 = (f & 31) * 4;
        float4 xv = make_float4(0.f, 0.f, 0.f, 0.f);
        if (rbase + r < NNODES) xv = ((const float4*)x)[(size_t)(rbase + r) * 32 + (f & 31)];
        unsigned int p0 = ((unsigned int)f2bf(xv.y) << 16) | f2bf(xv.x);
        unsigned int p1 = ((unsigned int)f2bf(xv.w) << 16) | f2bf(xv.z);
        *(uint2*)(As + r * AS_STRIDE + c4) = make_uint2(p0, p1);
    }
    // stage B: W[k][n] fp32 -> WT[n][k] bf16 LDS
    #pragma unroll
    for (int i = 0; i < 64; ++i) {
        int f = tid + i * 256;
        int k = f >> 7, n = f & 127;
        Bs[n * AS_STRIDE + k] = f2bf(W[f]);
    }
    __syncthreads();

    const int lane = tid & 63, w = tid >> 6;
    const int quad = lane >> 4, m16 = lane & 15;

    short8 af[4];
    #pragma unroll
    for (int s = 0; s < 4; ++s)
        af[s] = *(const short8*)(As + (w * 16 + m16) * AS_STRIDE + s * 32 + quad * 8);

    f32x4 acc[8];
    #pragma unroll
    for (int t = 0; t < 8; ++t) acc[t] = (f32x4){0.f, 0.f, 0.f, 0.f};

    #pragma unroll
    for (int t = 0; t < 8; ++t) {
        #pragma unroll
        for (int s = 0; s < 4; ++s) {
            short8 bf = *(const short8*)(Bs + (t * 16 + m16) * AS_STRIDE + s * 32 + quad * 8);
            acc[t] = __builtin_amdgcn_mfma_f32_16x16x32_bf16(af[s], bf, acc[t], 0, 0, 0);
        }
    }
    __syncthreads();   // done reading As/Bs; safe to alias with Cs

    // C layout: col = lane&15 (within tile), row = quad*4 + reg
    #pragma unroll
    for (int t = 0; t < 8; ++t)
        #pragma unroll
        for (int r = 0; r < 4; ++r)
            Cs[(w * 16 + quad * 4 + r) * CS_STRIDE + t * 16 + m16] = acc[t][r];
    __syncthreads();

    // epilogue: bf16 store + fused logits. lane cp = col pair (cols 2cp,2cp+1)
    const int cp = lane;
    float2 as_v = ((const float2*)att_src)[cp];
    float2 ad_v = ((const float2*)att_dst)[cp];
    #pragma unroll
    for (int r = 0; r < 16; ++r) {
        int row = w * 16 + r;
        int row_g = rbase + row;
        float2 cv = *(const float2*)(Cs + row * CS_STRIDE + 2 * cp);
        ushort2 hs;
        hs.x = f2bf(cv.x); hs.y = f2bf(cv.y);
        if (row_g < NNODES) ((ushort2*)(hb + (size_t)row_g * 128))[cp] = hs;
        float ps = cv.x * as_v.x + cv.y * as_v.y;
        float pd = cv.x * ad_v.x + cv.y * ad_v.y;
        #pragma unroll
        for (int m = 8; m >= 1; m >>= 1) {
            ps += __shfl_xor(ps, m, 16);
            pd += __shfl_xor(pd, m, 16);
        }
        if (row_g < NNODES && (cp & 15) == 0) {
            a_src[row_g * 4 + (cp >> 4)] = ps;
            a_dst[row_g * 4 + (cp >> 4)] = pd;
        }
    }
}

// K2: bin edges by dst>>8 into per-bucket global regions (LDS-staged, full-line writes)
__global__ __launch_bounds__(256) void bin_k(const int* __restrict__ ei,
                                             int* __restrict__ bcnt,
                                             unsigned int* __restrict__ bktdata) {
    __shared__ int lhist[NBKT];
    __shared__ int lofs[NBKT];
    __shared__ int lcur[NBKT];
    __shared__ int gbase[NBKT];
    __shared__ unsigned int staged[4096];
    const int b = blockIdx.x, t = threadIdx.x;
    for (int i = t; i < NBKT; i += 256) lhist[i] = 0;
    __syncthreads();
    unsigned int pk[16];
    int bk[16];
    const int e0 = b * 4096;
    #pragma unroll
    for (int i = 0; i < 16; ++i) {
        int e = e0 + i * 256 + t;
        if (e < NEDGES) {
            int s = ei[e], d = ei[NEDGES + e];
            bk[i] = d >> 8;
            pk[i] = ((unsigned)bk[i] << 24) | ((unsigned)(d & 255) << 16) | (unsigned)s;
            atomicAdd(&lhist[bk[i]], 1);
        } else bk[i] = -1;
    }
    __syncthreads();
    int v = (t < NBKT) ? lhist[t] : 0;
    int excl = block_excl_scan(v, t);
    if (t < NBKT) { lofs[t] = excl; lcur[t] = excl; }
    __syncthreads();
    if (t < NBKT) gbase[t] = (v > 0) ? atomicAdd(&bcnt[t], v) : 0;
    #pragma unroll
    for (int i = 0; i < 16; ++i) {
        if (bk[i] >= 0) {
            int pos = atomicAdd(&lcur[bk[i]], 1);
            staged[pos] = pk[i];
        }
    }
    __syncthreads();
    const int total = lofs[NBKT - 1] + lhist[NBKT - 1];
    for (int i = t; i < total; i += 256) {
        unsigned int ent = staged[i];
        int bb = ent >> 24;
        int pos = gbase[bb] + (i - lofs[bb]);
        bktdata[(size_t)bb * BCAP + pos] = ent & 0x00FFFFFFu;
    }
}

// K3: scan the 196 bucket totals -> csr base per bucket
__global__ __launch_bounds__(256) void bscan_k(const int* __restrict__ bcnt,
                                               int* __restrict__ bktoff) {
    const int t = threadIdx.x;
    int v = (t < NBKT) ? bcnt[t] : 0;
    int excl = block_excl_scan(v, t);
    if (t < NBKT) bktoff[t] = excl;
}

// K4: per-bucket counting sort in LDS; writes off (coalesced) + csr (coalesced).
__global__ __launch_bounds__(256) void sort_k(const int* __restrict__ bcnt,
                                              const int* __restrict__ bktoff,
                                              const unsigned int* __restrict__ bktdata,
                                              int* __restrict__ off,
                                              int* __restrict__ csr) {
    __shared__ unsigned int staged[BCAP];
    __shared__ int sorted[BCAP];
    __shared__ int lcnt[256];
    __shared__ int lcur[256];
    const int b = blockIdx.x, t = threadIdx.x;
    const int cnt = bcnt[b], base = bktoff[b];
    lcnt[t] = 0;
    for (int i = t; i < cnt; i += 256) staged[i] = bktdata[(size_t)b * BCAP + i];
    __syncthreads();
    for (int i = t; i < cnt; i += 256) atomicAdd(&lcnt[staged[i] >> 16], 1);
    __syncthreads();
    int v = lcnt[t];
    int excl = block_excl_scan(v, t);
    lcur[t] = excl;
    const int node = b * 256 + t;
    if (node <= NNODES) off[node] = base + excl;
    __syncthreads();
    for (int i = t; i < cnt; i += 256) {
        unsigned int ent = staged[i];
        int pos = atomicAdd(&lcur[ent >> 16], 1);
        sorted[pos] = (int)(ent & 0xFFFFu);
    }
    __syncthreads();
    for (int i = t; i < cnt; i += 256) csr[base + i] = sorted[i];
}

// K5: gather per dst node, uint4 (8-channel) lanes, 4 edges in flight.
// CORRECTNESS NOTE (R9 bug): __shfl = ds_bpermute reads UNDEFINED data from
// EXEC-inactive source lanes. The shfls below MUST stay outside any divergent
// branch (the j<m guard is divergent on tail chunks); only the load+FMA is
// guarded. Whole wave executes the shfls; garbage wj/sj for j>=m are unused.
__global__ __launch_bounds__(256) void gather_k(const int* __restrict__ off,
                                                const int* __restrict__ csr,
                                                const unsigned short* __restrict__ hb,
                                                const float* __restrict__ a_src,
                                                const float* __restrict__ a_dst,
                                                const float* __restrict__ bias,
                                                float* __restrict__ out) {
    const int wid = threadIdx.x >> 6, lane = threadIdx.x & 63;
    const int n = blockIdx.x * 4 + wid;
    if (n >= NNODES) return;
    const int head = lane >> 4;      // weight-phase head (also load group g)
    const int sub  = lane & 15;      // weight-phase edge slot (also chunk idx q)
    const int g = head, q = sub;
    const int head_c = q >> 2;       // head of the channels this lane accumulates

    const float a_d = a_dst[n * 4 + head];
    float acc[8];
    #pragma unroll
    for (int k = 0; k < 8; ++k) acc[k] = 0.f;

    // self-loop: group 0 seeds acc with w_self(head_c) * h[n]
    if (g == 0) {
        float wsc = __expf(leaky(a_src[n * 4 + head_c] + a_dst[n * 4 + head_c]));
        uint4 hv = ((const uint4*)(hb + (size_t)n * 128))[q];
        acc[0] = wsc * __uint_as_float(hv.x << 16);
        acc[1] = wsc * __uint_as_float(hv.x & 0xffff0000u);
        acc[2] = wsc * __uint_as_float(hv.y << 16);
        acc[3] = wsc * __uint_as_float(hv.y & 0xffff0000u);
        acc[4] = wsc * __uint_as_float(hv.z << 16);
        acc[5] = wsc * __uint_as_float(hv.z & 0xffff0000u);
        acc[6] = wsc * __uint_as_float(hv.w << 16);
        acc[7] = wsc * __uint_as_float(hv.w & 0xffff0000u);
    }
    // denom: per-(head) partial, seeded once per head group with w_self(head)
    float denom = (sub == 0) ? __expf(leaky(a_src[n * 4 + head] + a_d)) : 0.f;

    const int beg = off[n], end = off[n + 1];
    for (int base = beg; base < end; base += 16) {
        int m = end - base; if (m > 16) m = 16;
        int s = 0;
        float w = 0.f;
        if (sub < m) {
            s = csr[base + sub];
            w = __expf(leaky(a_src[s * 4 + head] + a_d));
        }
        denom += w;
        #pragma unroll
        for (int jj = 0; jj < 4; ++jj) {
            int j = jj * 4 + g;
            int   sj = __shfl(s, j);                       // wave-uniform execution
            float wj = __shfl(w, (head_c << 4) | j);       // wave-uniform execution
            if (j < m) {
                uint4 hv = ((const uint4*)(hb + (size_t)sj * 128))[q];
                acc[0] += wj * __uint_as_float(hv.x << 16);
                acc[1] += wj * __uint_as_float(hv.x & 0xffff0000u);
                acc[2] += wj * __uint_as_float(hv.y << 16);
                acc[3] += wj * __uint_as_float(hv.y & 0xffff0000u);
                acc[4] += wj * __uint_as_float(hv.z << 16);
                acc[5] += wj * __uint_as_float(hv.z & 0xffff0000u);
                acc[6] += wj * __uint_as_float(hv.w << 16);
                acc[7] += wj * __uint_as_float(hv.w & 0xffff0000u);
            }
        }
    }
    // reduce denom within each head group (16-wide butterfly), fetch for head_c
    #pragma unroll
    for (int mm = 8; mm >= 1; mm >>= 1) denom += __shfl_xor(denom, mm, 16);
    const float inv = __frcp_rn(__shfl(denom, head_c << 4));
    // merge the 4 load groups (lanes l, l+16, l+32, l+48 hold same channels)
    #pragma unroll
    for (int k = 0; k < 8; ++k) {
        acc[k] += __shfl_xor(acc[k], 16);
        acc[k] += __shfl_xor(acc[k], 32);
    }
    if (g == 0) {
        float4 b0 = ((const float4*)bias)[2 * q];
        float4 b1 = ((const float4*)bias)[2 * q + 1];
        float4* orow = (float4*)(out + (size_t)n * 128);
        orow[2 * q]     = make_float4(acc[0] * inv + b0.x, acc[1] * inv + b0.y,
                                      acc[2] * inv + b0.z, acc[3] * inv + b0.w);
        orow[2 * q + 1] = make_float4(acc[4] * inv + b1.x, acc[5] * inv + b1.y,
                                      acc[6] * inv + b1.z, acc[7] * inv + b1.w);
    }
}

extern "C" void kernel_launch(void* const* d_in, const int* in_sizes, int n_in,
                              void* d_out, int out_size, void* d_ws, size_t ws_size,
                              hipStream_t stream) {
    const float* x     = (const float*)d_in[0];
    const int*   ei    = (const int*)d_in[1];   // int64 ref -> delivered int32
    const float* W     = (const float*)d_in[2];
    const float* att_s = (const float*)d_in[3];
    const float* att_d = (const float*)d_in[4];
    const float* bias  = (const float*)d_in[5];
    float*       out   = (float*)d_out;
    char*        ws    = (char*)d_ws;

    // ws layout (bytes):
    // hb (bf16) 12.8MB | a_src 0.8MB | a_dst 0.8MB | off 50177*4 | csr 3.2MB |
    // bktdata 196*5120*4 = 4.01MB | bcnt 784B | bktoff 784B
    unsigned short* hb = (unsigned short*)(ws);
    float* a_src  = (float*)(ws + 12800000);
    float* a_dst  = (float*)(ws + 13600000);
    int*   off    = (int*)  (ws + 14400000);
    int*   csr    = (int*)  (ws + 14600768);
    unsigned int* bktdata = (unsigned int*)(ws + 17800768);
    int*   bcnt   = (int*)  (ws + 21814848);
    int*   bktoff = (int*)  (ws + 21815680);

    hipMemsetAsync(bcnt, 0, NBKT * sizeof(int), stream);
    gemm_k  <<<782,   256, 0, stream>>>(x, W, hb, att_s, att_d, a_src, a_dst);
    bin_k   <<<196,   256, 0, stream>>>(ei, bcnt, bktdata);
    bscan_k <<<1,     256, 0, stream>>>(bcnt, bktoff);
    sort_k  <<<196,   256, 0, stream>>>(bcnt, bktoff, bktdata, off, csr);
    gather_k<<<12500, 256, 0, stream>>>(off, csr, hb, a_src, a_dst, bias, out);
}

// Round 12
// 163.801 us; speedup vs baseline: 1.0385x; 1.0385x over previous
//
#include <hip/hip_runtime.h>
#include <cstdint>

#define NNODES 50000
#define NEDGES 800000
#define NEG 0.2f
#define NBKT 196        // buckets of 256 nodes: 196*256 = 50176 >= 50000
#define BCAP 5120       // per-bucket capacity (mean 4096, sd 64 -> 16 sigma headroom)
#define GEMM_BLOCKS 782 // ceil(50000/64)

typedef __attribute__((ext_vector_type(8))) short short8;   // 8 bf16 (4 VGPRs)
typedef __attribute__((ext_vector_type(4))) float f32x4;

#define AS_STRIDE 136   // ushorts; 272B rows -> 16B aligned
#define CS_STRIDE 132   // floats; breaks 128-mod-32 bank aliasing

__device__ __forceinline__ float leaky(float v) { return v > 0.f ? v : NEG * v; }

__device__ __forceinline__ unsigned short f2bf(float f) {   // round-to-nearest-even
    unsigned int u = __float_as_uint(f);
    u += 0x7fff + ((u >> 16) & 1);
    return (unsigned short)(u >> 16);
}

// 256-thread block exclusive scan (shfl within wave + LDS across 4 waves)
__device__ __forceinline__ int block_excl_scan(int v, int t) {
    __shared__ int wsum[4];
    const int lane = t & 63, wv = t >> 6;
    int x = v;
    #pragma unroll
    for (int m = 1; m < 64; m <<= 1) {
        int u = __shfl_up(x, m);
        if (lane >= m) x += u;
    }
    if (lane == 63) wsum[wv] = x;
    __syncthreads();
    if (t == 0) {
        int run = 0;
        #pragma unroll
        for (int i = 0; i < 4; ++i) { int tmp = wsum[i]; wsum[i] = run; run += tmp; }
    }
    __syncthreads();
    return x - v + wsum[wv];
}

// K1 (fused): blocks [0,782) = bf16-MFMA gemm (h=x@W, bf16 store, fused logits);
// blocks [782,978) = edge binning by dst>>8 (LDS-staged, full-line writes).
// Independent inputs -> co-scheduled instead of serialized.
__global__ __launch_bounds__(256) void fused_k(const float* __restrict__ x,
                                               const float* __restrict__ W,
                                               unsigned short* __restrict__ hb,
                                               const float* __restrict__ att_src,
                                               const float* __restrict__ att_dst,
                                               float* __restrict__ a_src,
                                               float* __restrict__ a_dst,
                                               const int* __restrict__ ei,
                                               int* __restrict__ bcnt,
                                               unsigned int* __restrict__ bktdata) {
    __shared__ __align__(16) char smem[52224];
    const int tid = threadIdx.x;

    if (blockIdx.x < GEMM_BLOCKS) {
        // ---------------- GEMM part ----------------
        unsigned short* As = (unsigned short*)smem;            // [64][AS_STRIDE] bf16
        unsigned short* Bs = (unsigned short*)(smem + 17408);  // WT [128][AS_STRIDE] bf16
        float*          Cs = (float*)smem;                     // [64][CS_STRIDE] fp32 (aliases)
        const int rbase = blockIdx.x * 64;

        // stage A: x rows fp32 -> bf16 LDS
        #pragma unroll
        for (int i = 0; i < 8; ++i) {
            int f = tid + i * 256;           // float4 index; 32 per row
            int r = f >> 5, c4 = (f & 31) * 4;
            float4 xv = make_float4(0.f, 0.f, 0.f, 0.f);
            if (rbase + r < NNODES) xv = ((const float4*)x)[(size_t)(rbase + r) * 32 + (f & 31)];
            unsigned int p0 = ((unsigned int)f2bf(xv.y) << 16) | f2bf(xv.x);
            unsigned int p1 = ((unsigned int)f2bf(xv.w) << 16) | f2bf(xv.z);
            *(uint2*)(As + r * AS_STRIDE + c4) = make_uint2(p0, p1);
        }
        // stage B: W[k][n] fp32 -> WT[n][k] bf16 LDS (float4 loads)
        #pragma unroll
        for (int i = 0; i < 16; ++i) {
            int f4 = tid + i * 256;          // [0,4096)
            int k = f4 >> 5, n4 = (f4 & 31) * 4;
            float4 wv = ((const float4*)W)[f4];
            Bs[(n4 + 0) * AS_STRIDE + k] = f2bf(wv.x);
            Bs[(n4 + 1) * AS_STRIDE + k] = f2bf(wv.y);
            Bs[(n4 + 2) * AS_STRIDE + k] = f2bf(wv.z);
            Bs[(n4 + 3) * AS_STRIDE + k] = f2bf(wv.w);
        }
        __syncthreads();

        const int lane = tid & 63, w = tid >> 6;
        const int quad = lane >> 4, m16 = lane & 15;

        short8 af[4];
        #pragma unroll
        for (int s = 0; s < 4; ++s)
            af[s] = *(const short8*)(As + (w * 16 + m16) * AS_STRIDE + s * 32 + quad * 8);

        f32x4 acc[8];
        #pragma unroll
        for (int t = 0; t < 8; ++t) acc[t] = (f32x4){0.f, 0.f, 0.f, 0.f};

        #pragma unroll
        for (int t = 0; t < 8; ++t) {
            #pragma unroll
            for (int s = 0; s < 4; ++s) {
                short8 bf = *(const short8*)(Bs + (t * 16 + m16) * AS_STRIDE + s * 32 + quad * 8);
                acc[t] = __builtin_amdgcn_mfma_f32_16x16x32_bf16(af[s], bf, acc[t], 0, 0, 0);
            }
        }
        __syncthreads();   // done reading As/Bs; safe to alias with Cs

        // C layout: col = lane&15 (within tile), row = quad*4 + reg
        #pragma unroll
        for (int t = 0; t < 8; ++t)
            #pragma unroll
            for (int r = 0; r < 4; ++r)
                Cs[(w * 16 + quad * 4 + r) * CS_STRIDE + t * 16 + m16] = acc[t][r];
        __syncthreads();

        // epilogue: bf16 store + fused logits. lane cp = col pair
        const int cp = lane;
        float2 as_v = ((const float2*)att_src)[cp];
        float2 ad_v = ((const float2*)att_dst)[cp];
        #pragma unroll
        for (int r = 0; r < 16; ++r) {
            int row = w * 16 + r;
            int row_g = rbase + row;
            float2 cv = *(const float2*)(Cs + row * CS_STRIDE + 2 * cp);
            ushort2 hs;
            hs.x = f2bf(cv.x); hs.y = f2bf(cv.y);
            if (row_g < NNODES) ((ushort2*)(hb + (size_t)row_g * 128))[cp] = hs;
            float ps = cv.x * as_v.x + cv.y * as_v.y;
            float pd = cv.x * ad_v.x + cv.y * ad_v.y;
            #pragma unroll
            for (int m = 8; m >= 1; m >>= 1) {
                ps += __shfl_xor(ps, m, 16);
                pd += __shfl_xor(pd, m, 16);
            }
            if (row_g < NNODES && (cp & 15) == 0) {
                a_src[row_g * 4 + (cp >> 4)] = ps;
                a_dst[row_g * 4 + (cp >> 4)] = pd;
            }
        }
    } else {
        // ---------------- BIN part ----------------
        int* lhist = (int*)smem;                    // [NBKT]
        int* lofs  = lhist + NBKT;
        int* lcur  = lofs + NBKT;
        int* gbase = lcur + NBKT;
        unsigned int* staged = (unsigned int*)(gbase + NBKT);  // [4096]
        const int b = blockIdx.x - GEMM_BLOCKS, t = tid;
        for (int i = t; i < NBKT; i += 256) lhist[i] = 0;
        __syncthreads();
        unsigned int pk[16];
        int bk[16];
        const int e0 = b * 4096;
        #pragma unroll
        for (int i = 0; i < 16; ++i) {
            int e = e0 + i * 256 + t;
            if (e < NEDGES) {
                int s = ei[e], d = ei[NEDGES + e];
                bk[i] = d >> 8;
                pk[i] = ((unsigned)bk[i] << 24) | ((unsigned)(d & 255) << 16) | (unsigned)s;
                atomicAdd(&lhist[bk[i]], 1);
            } else bk[i] = -1;
        }
        __syncthreads();
        int v = (t < NBKT) ? lhist[t] : 0;
        int excl = block_excl_scan(v, t);
        if (t < NBKT) { lofs[t] = excl; lcur[t] = excl; }
        __syncthreads();
        if (t < NBKT) gbase[t] = (v > 0) ? atomicAdd(&bcnt[t], v) : 0;
        #pragma unroll
        for (int i = 0; i < 16; ++i) {
            if (bk[i] >= 0) {
                int pos = atomicAdd(&lcur[bk[i]], 1);
                staged[pos] = pk[i];
            }
        }
        __syncthreads();
        const int total = lofs[NBKT - 1] + lhist[NBKT - 1];
        for (int i = t; i < total; i += 256) {
            unsigned int ent = staged[i];
            int bb = ent >> 24;
            int pos = gbase[bb] + (i - lofs[bb]);
            bktdata[(size_t)bb * BCAP + pos] = ent & 0x00FFFFFFu;
        }
    }
}

// K2: per-bucket counting sort in LDS; computes its csr base by scanning bcnt
// in-block (replaces the separate bscan dispatch). Writes off + csr coalesced.
__global__ __launch_bounds__(256) void sort_k(const int* __restrict__ bcnt,
                                              const unsigned int* __restrict__ bktdata,
                                              int* __restrict__ off,
                                              int* __restrict__ csr) {
    __shared__ unsigned int staged[BCAP];
    __shared__ int sorted[BCAP];
    __shared__ int lcnt[256];
    __shared__ int lcur[256];
    __shared__ int sbase, scnt;
    const int b = blockIdx.x, t = threadIdx.x;
    // in-block scan of bucket totals -> this bucket's base
    int bv = (t < NBKT) ? bcnt[t] : 0;
    int bexcl = block_excl_scan(bv, t);
    if (t == b) { sbase = bexcl; scnt = bv; }
    __syncthreads();
    const int cnt = scnt, base = sbase;
    lcnt[t] = 0;
    for (int i = t; i < cnt; i += 256) staged[i] = bktdata[(size_t)b * BCAP + i];
    __syncthreads();
    for (int i = t; i < cnt; i += 256) atomicAdd(&lcnt[staged[i] >> 16], 1);
    __syncthreads();
    int v = lcnt[t];
    int excl = block_excl_scan(v, t);
    lcur[t] = excl;
    const int node = b * 256 + t;
    if (node <= NNODES) off[node] = base + excl;
    __syncthreads();
    for (int i = t; i < cnt; i += 256) {
        unsigned int ent = staged[i];
        int pos = atomicAdd(&lcur[ent >> 16], 1);
        sorted[pos] = (int)(ent & 0xFFFFu);
    }
    __syncthreads();
    for (int i = t; i < cnt; i += 256) csr[base + i] = sorted[i];
}

// K3: gather per dst node, uint4 (8-channel) lanes, 4 edges in flight.
// CORRECTNESS NOTE: __shfl = ds_bpermute reads UNDEFINED data from
// EXEC-inactive source lanes -> shfls stay OUTSIDE the divergent j<m guard.
__global__ __launch_bounds__(256) void gather_k(const int* __restrict__ off,
                                                const int* __restrict__ csr,
                                                const unsigned short* __restrict__ hb,
                                                const float* __restrict__ a_src,
                                                const float* __restrict__ a_dst,
                                                const float* __restrict__ bias,
                                                float* __restrict__ out) {
    const int wid = threadIdx.x >> 6, lane = threadIdx.x & 63;
    const int n = blockIdx.x * 4 + wid;
    if (n >= NNODES) return;
    const int head = lane >> 4;      // weight-phase head (also load group g)
    const int sub  = lane & 15;      // weight-phase edge slot (also chunk idx q)
    const int g = head, q = sub;
    const int head_c = q >> 2;       // head of the channels this lane accumulates

    const float a_d = a_dst[n * 4 + head];
    float acc[8];
    #pragma unroll
    for (int k = 0; k < 8; ++k) acc[k] = 0.f;

    if (g == 0) {   // self-loop seeds group 0
        float wsc = __expf(leaky(a_src[n * 4 + head_c] + a_dst[n * 4 + head_c]));
        uint4 hv = ((const uint4*)(hb + (size_t)n * 128))[q];
        acc[0] = wsc * __uint_as_float(hv.x << 16);
        acc[1] = wsc * __uint_as_float(hv.x & 0xffff0000u);
        acc[2] = wsc * __uint_as_float(hv.y << 16);
        acc[3] = wsc * __uint_as_float(hv.y & 0xffff0000u);
        acc[4] = wsc * __uint_as_float(hv.z << 16);
        acc[5] = wsc * __uint_as_float(hv.z & 0xffff0000u);
        acc[6] = wsc * __uint_as_float(hv.w << 16);
        acc[7] = wsc * __uint_as_float(hv.w & 0xffff0000u);
    }
    float denom = (sub == 0) ? __expf(leaky(a_src[n * 4 + head] + a_d)) : 0.f;

    const int beg = off[n], end = off[n + 1];
    for (int base = beg; base < end; base += 16) {
        int m = end - base; if (m > 16) m = 16;
        int s = 0;
        float w = 0.f;
        if (sub < m) {
            s = csr[base + sub];
            w = __expf(leaky(a_src[s * 4 + head] + a_d));
        }
        denom += w;
        #pragma unroll
        for (int jj = 0; jj < 4; ++jj) {
            int j = jj * 4 + g;
            int   sj = __shfl(s, j);                       // wave-uniform execution
            float wj = __shfl(w, (head_c << 4) | j);       // wave-uniform execution
            if (j < m) {
                uint4 hv = ((const uint4*)(hb + (size_t)sj * 128))[q];
                acc[0] += wj * __uint_as_float(hv.x << 16);
                acc[1] += wj * __uint_as_float(hv.x & 0xffff0000u);
                acc[2] += wj * __uint_as_float(hv.y << 16);
                acc[3] += wj * __uint_as_float(hv.y & 0xffff0000u);
                acc[4] += wj * __uint_as_float(hv.z << 16);
                acc[5] += wj * __uint_as_float(hv.z & 0xffff0000u);
                acc[6] += wj * __uint_as_float(hv.w << 16);
                acc[7] += wj * __uint_as_float(hv.w & 0xffff0000u);
            }
        }
    }
    #pragma unroll
    for (int mm = 8; mm >= 1; mm >>= 1) denom += __shfl_xor(denom, mm, 16);
    const float inv = __frcp_rn(__shfl(denom, head_c << 4));
    #pragma unroll
    for (int k = 0; k < 8; ++k) {
        acc[k] += __shfl_xor(acc[k], 16);
        acc[k] += __shfl_xor(acc[k], 32);
    }
    if (g == 0) {
        float4 b0 = ((const float4*)bias)[2 * q];
        float4 b1 = ((const float4*)bias)[2 * q + 1];
        float4* orow = (float4*)(out + (size_t)n * 128);
        orow[2 * q]     = make_float4(acc[0] * inv + b0.x, acc[1] * inv + b0.y,
                                      acc[2] * inv + b0.z, acc[3] * inv + b0.w);
        orow[2 * q + 1] = make_float4(acc[4] * inv + b1.x, acc[5] * inv + b1.y,
                                      acc[6] * inv + b1.z, acc[7] * inv + b1.w);
    }
}

extern "C" void kernel_launch(void* const* d_in, const int* in_sizes, int n_in,
                              void* d_out, int out_size, void* d_ws, size_t ws_size,
                              hipStream_t stream) {
    const float* x     = (const float*)d_in[0];
    const int*   ei    = (const int*)d_in[1];   // int64 ref -> delivered int32
    const float* W     = (const float*)d_in[2];
    const float* att_s = (const float*)d_in[3];
    const float* att_d = (const float*)d_in[4];
    const float* bias  = (const float*)d_in[5];
    float*       out   = (float*)d_out;
    char*        ws    = (char*)d_ws;

    // ws layout (bytes):
    // hb (bf16) 12.8MB | a_src 0.8MB | a_dst 0.8MB | off 50177*4 | csr 3.2MB |
    // bktdata 196*5120*4 = 4.01MB | bcnt 784B
    unsigned short* hb = (unsigned short*)(ws);
    float* a_src  = (float*)(ws + 12800000);
    float* a_dst  = (float*)(ws + 13600000);
    int*   off    = (int*)  (ws + 14400000);
    int*   csr    = (int*)  (ws + 14600768);
    unsigned int* bktdata = (unsigned int*)(ws + 17800768);
    int*   bcnt   = (int*)  (ws + 21814848);

    hipMemsetAsync(bcnt, 0, NBKT * sizeof(int), stream);
    fused_k <<<GEMM_BLOCKS + NBKT, 256, 0, stream>>>(x, W, hb, att_s, att_d,
                                                     a_src, a_dst, ei, bcnt, bktdata);
    sort_k  <<<NBKT,  256, 0, stream>>>(bcnt, bktdata, off, csr);
    gather_k<<<12500, 256, 0, stream>>>(off, csr, hb, a_src, a_dst, bias, out);
}